// Round 3
// baseline (92.132 us; speedup 1.0000x reference)
//
#include <hip/hip_runtime.h>

#define NPTS 16384
#define NSPLIT 64
#define CHUNK (NPTS / NSPLIT)        // 256 sources per chunk
#define TPT 8                        // targets per thread
#define TBLK (NPTS / (256 * TPT))    // 8 target blocks -> grid 8x64 = 512 blocks

// Kernel 1: per (target-block, source-chunk) partial MIN of d2 = ||s||^2 - 2 t.s.
// 3 FMA + 0.5 min3 per pair; 8 independent min chains/thread for latency hiding.
__global__ __launch_bounds__(256) void nn_min(const float* __restrict__ src,
                                              const float* __restrict__ tar,
                                              float* __restrict__ ws) {
    __shared__ float4 sp[CHUNK];
    const int tid = threadIdx.x;
    const int tb  = blockIdx.x;
    const int sc  = blockIdx.y;
    const int sbase = sc * CHUNK;

    {
        const int i = tid;
        if (i < CHUNK) {
            float x = src[(sbase + i) * 3 + 0];
            float y = src[(sbase + i) * 3 + 1];
            float z = src[(sbase + i) * 3 + 2];
            sp[i] = make_float4(-2.0f * x, -2.0f * y, -2.0f * z, x * x + y * y + z * z);
        }
    }
    __syncthreads();

    const int t0 = tb * (256 * TPT) + tid;
    float tx[TPT], ty[TPT], tz[TPT], best[TPT];
#pragma unroll
    for (int k = 0; k < TPT; ++k) {
        const int t = t0 + k * 256;
        tx[k] = tar[t * 3 + 0];
        ty[k] = tar[t * 3 + 1];
        tz[k] = tar[t * 3 + 2];
        best[k] = 1e30f;
    }

#pragma unroll 4
    for (int j = 0; j < CHUNK; j += 2) {
        float4 sA = sp[j];
        float4 sB = sp[j + 1];
#pragma unroll
        for (int k = 0; k < TPT; ++k) {
            float dA = fmaf(tx[k], sA.x, fmaf(ty[k], sA.y, fmaf(tz[k], sA.z, sA.w)));
            float dB = fmaf(tx[k], sB.x, fmaf(ty[k], sB.y, fmaf(tz[k], sB.z, sB.w)));
            best[k] = fminf(best[k], fminf(dA, dB));   // fuses to v_min3_f32
        }
    }
#pragma unroll
    for (int k = 0; k < TPT; ++k)
        ws[sc * NPTS + t0 + k * 256] = best[k];
}

// Kernel 2: reduce NSPLIT partial mins per target, add ||t||^2, sum 0.5*d2 into out.
__global__ __launch_bounds__(256) void nn_sum(const float* __restrict__ tar,
                                              const float* __restrict__ ws,
                                              float* __restrict__ out) {
    const int t = blockIdx.x * 256 + threadIdx.x;
    float best = 1e30f;
#pragma unroll 8
    for (int sc = 0; sc < NSPLIT; ++sc)
        best = fminf(best, ws[sc * NPTS + t]);
    const float tx = tar[t * 3 + 0], ty = tar[t * 3 + 1], tz = tar[t * 3 + 2];
    float v = 0.5f * (best + tx * tx + ty * ty + tz * tz);   // 0.5*||t-s||^2

    for (int off = 32; off > 0; off >>= 1) v += __shfl_down(v, off, 64);
    __shared__ float wsum[4];
    const int lane = threadIdx.x & 63, wv = threadIdx.x >> 6;
    if (lane == 0) wsum[wv] = v;
    __syncthreads();
    if (threadIdx.x == 0) atomicAdd(out, wsum[0] + wsum[1] + wsum[2] + wsum[3]);
}

// Fallback if d_ws is too small (not expected): single kernel, full sweep.
__global__ __launch_bounds__(256) void nn_all(const float* __restrict__ src,
                                              const float* __restrict__ tar,
                                              float* __restrict__ out) {
    __shared__ float4 sp[2048];
    const int tid = threadIdx.x;
    const int t = blockIdx.x * 256 + tid;
    const float tx = tar[t * 3 + 0], ty = tar[t * 3 + 1], tz = tar[t * 3 + 2];
    float best = 1e30f;
    for (int base = 0; base < NPTS; base += 2048) {
        __syncthreads();
        for (int i = tid; i < 2048; i += 256) {
            float x = src[(base + i) * 3 + 0];
            float y = src[(base + i) * 3 + 1];
            float z = src[(base + i) * 3 + 2];
            sp[i] = make_float4(-2.0f * x, -2.0f * y, -2.0f * z, x * x + y * y + z * z);
        }
        __syncthreads();
#pragma unroll 4
        for (int j = 0; j < 2048; j += 2) {
            float4 sA = sp[j], sB = sp[j + 1];
            float dA = fmaf(tx, sA.x, fmaf(ty, sA.y, fmaf(tz, sA.z, sA.w)));
            float dB = fmaf(tx, sB.x, fmaf(ty, sB.y, fmaf(tz, sB.z, sB.w)));
            best = fminf(best, fminf(dA, dB));
        }
    }
    float v = 0.5f * (best + tx * tx + ty * ty + tz * tz);
    for (int off = 32; off > 0; off >>= 1) v += __shfl_down(v, off, 64);
    __shared__ float wsum[4];
    const int lane = threadIdx.x & 63, wv = threadIdx.x >> 6;
    if (lane == 0) wsum[wv] = v;
    __syncthreads();
    if (threadIdx.x == 0) atomicAdd(out, wsum[0] + wsum[1] + wsum[2] + wsum[3]);
}

extern "C" void kernel_launch(void* const* d_in, const int* in_sizes, int n_in,
                              void* d_out, int out_size, void* d_ws, size_t ws_size,
                              hipStream_t stream) {
    const float* src = (const float*)d_in[0];
    const float* tar = (const float*)d_in[1];
    float* out = (float*)d_out;

    hipMemsetAsync(d_out, 0, sizeof(float) * (size_t)out_size, stream);

    const size_t need = (size_t)NSPLIT * NPTS * sizeof(float);   // 4 MB
    if (ws_size >= need) {
        nn_min<<<dim3(TBLK, NSPLIT), 256, 0, stream>>>(src, tar, (float*)d_ws);
        nn_sum<<<NPTS / 256, 256, 0, stream>>>(tar, (const float*)d_ws, out);
    } else {
        nn_all<<<NPTS / 256, 256, 0, stream>>>(src, tar, out);
    }
}

// Round 4
// 88.644 us; speedup vs baseline: 1.0393x; 1.0393x over previous
//
#include <hip/hip_runtime.h>

#define NPTS 16384
#define NSPLIT 64
#define CHUNK (NPTS / NSPLIT)        // 256 sources per chunk
#define TPT 4                        // targets per thread
#define TBLK (NPTS / (256 * TPT))    // 16 target blocks -> grid 16x64 = 1024 blocks (4/CU)

// Kernel 1: per (target-block, source-chunk) partial MIN of d2 = ||s||^2 - 2 t.s.
// 3 FMA + 0.5 min3 per pair; 4 independent min chains/thread; 4 blocks/CU.
__global__ __launch_bounds__(256) void nn_min(const float* __restrict__ src,
                                              const float* __restrict__ tar,
                                              float* __restrict__ ws) {
    __shared__ float4 sp[CHUNK];
    const int tid = threadIdx.x;
    const int tb  = blockIdx.x;
    const int sc  = blockIdx.y;
    const int sbase = sc * CHUNK;

    if (tid < CHUNK) {
        float x = src[(sbase + tid) * 3 + 0];
        float y = src[(sbase + tid) * 3 + 1];
        float z = src[(sbase + tid) * 3 + 2];
        sp[tid] = make_float4(-2.0f * x, -2.0f * y, -2.0f * z, x * x + y * y + z * z);
    }
    __syncthreads();

    const int t0 = tb * (256 * TPT) + tid;
    float tx[TPT], ty[TPT], tz[TPT], best[TPT];
#pragma unroll
    for (int k = 0; k < TPT; ++k) {
        const int t = t0 + k * 256;
        tx[k] = tar[t * 3 + 0];
        ty[k] = tar[t * 3 + 1];
        tz[k] = tar[t * 3 + 2];
        best[k] = 1e30f;
    }

#pragma unroll 2
    for (int j = 0; j < CHUNK; j += 4) {
        float4 s0 = sp[j + 0];
        float4 s1 = sp[j + 1];
        float4 s2 = sp[j + 2];
        float4 s3 = sp[j + 3];
#pragma unroll
        for (int k = 0; k < TPT; ++k) {
            float dA = fmaf(tx[k], s0.x, fmaf(ty[k], s0.y, fmaf(tz[k], s0.z, s0.w)));
            float dB = fmaf(tx[k], s1.x, fmaf(ty[k], s1.y, fmaf(tz[k], s1.z, s1.w)));
            float dC = fmaf(tx[k], s2.x, fmaf(ty[k], s2.y, fmaf(tz[k], s2.z, s2.w)));
            float dD = fmaf(tx[k], s3.x, fmaf(ty[k], s3.y, fmaf(tz[k], s3.z, s3.w)));
            float m  = fminf(fminf(dA, dB), dC);           // v_min3_f32
            best[k]  = fminf(fminf(best[k], m), dD);       // v_min3_f32
        }
    }
#pragma unroll
    for (int k = 0; k < TPT; ++k)
        ws[sc * NPTS + t0 + k * 256] = best[k];
}

// Kernel 2: reduce NSPLIT partial mins per target, add ||t||^2, sum 0.5*d2 into out.
__global__ __launch_bounds__(256) void nn_sum(const float* __restrict__ tar,
                                              const float* __restrict__ ws,
                                              float* __restrict__ out) {
    const int t = blockIdx.x * 256 + threadIdx.x;
    float best = 1e30f;
#pragma unroll 8
    for (int sc = 0; sc < NSPLIT; ++sc)
        best = fminf(best, ws[sc * NPTS + t]);
    const float tx = tar[t * 3 + 0], ty = tar[t * 3 + 1], tz = tar[t * 3 + 2];
    float v = 0.5f * (best + tx * tx + ty * ty + tz * tz);   // 0.5*||t-s||^2

    for (int off = 32; off > 0; off >>= 1) v += __shfl_down(v, off, 64);
    __shared__ float wsum[4];
    const int lane = threadIdx.x & 63, wv = threadIdx.x >> 6;
    if (lane == 0) wsum[wv] = v;
    __syncthreads();
    if (threadIdx.x == 0) atomicAdd(out, wsum[0] + wsum[1] + wsum[2] + wsum[3]);
}

// Fallback if d_ws is too small (not expected): single kernel, full sweep.
__global__ __launch_bounds__(256) void nn_all(const float* __restrict__ src,
                                              const float* __restrict__ tar,
                                              float* __restrict__ out) {
    __shared__ float4 sp[2048];
    const int tid = threadIdx.x;
    const int t = blockIdx.x * 256 + tid;
    const float tx = tar[t * 3 + 0], ty = tar[t * 3 + 1], tz = tar[t * 3 + 2];
    float best = 1e30f;
    for (int base = 0; base < NPTS; base += 2048) {
        __syncthreads();
        for (int i = tid; i < 2048; i += 256) {
            float x = src[(base + i) * 3 + 0];
            float y = src[(base + i) * 3 + 1];
            float z = src[(base + i) * 3 + 2];
            sp[i] = make_float4(-2.0f * x, -2.0f * y, -2.0f * z, x * x + y * y + z * z);
        }
        __syncthreads();
#pragma unroll 2
        for (int j = 0; j < 2048; j += 4) {
            float4 s0 = sp[j], s1 = sp[j + 1], s2 = sp[j + 2], s3 = sp[j + 3];
            float dA = fmaf(tx, s0.x, fmaf(ty, s0.y, fmaf(tz, s0.z, s0.w)));
            float dB = fmaf(tx, s1.x, fmaf(ty, s1.y, fmaf(tz, s1.z, s1.w)));
            float dC = fmaf(tx, s2.x, fmaf(ty, s2.y, fmaf(tz, s2.z, s2.w)));
            float dD = fmaf(tx, s3.x, fmaf(ty, s3.y, fmaf(tz, s3.z, s3.w)));
            float m  = fminf(fminf(dA, dB), dC);
            best     = fminf(fminf(best, m), dD);
        }
    }
    float v = 0.5f * (best + tx * tx + ty * ty + tz * tz);
    for (int off = 32; off > 0; off >>= 1) v += __shfl_down(v, off, 64);
    __shared__ float wsum[4];
    const int lane = threadIdx.x & 63, wv = threadIdx.x >> 6;
    if (lane == 0) wsum[wv] = v;
    __syncthreads();
    if (threadIdx.x == 0) atomicAdd(out, wsum[0] + wsum[1] + wsum[2] + wsum[3]);
}

extern "C" void kernel_launch(void* const* d_in, const int* in_sizes, int n_in,
                              void* d_out, int out_size, void* d_ws, size_t ws_size,
                              hipStream_t stream) {
    const float* src = (const float*)d_in[0];
    const float* tar = (const float*)d_in[1];
    float* out = (float*)d_out;

    hipMemsetAsync(d_out, 0, sizeof(float) * (size_t)out_size, stream);

    const size_t need = (size_t)NSPLIT * NPTS * sizeof(float);   // 4 MB
    if (ws_size >= need) {
        nn_min<<<dim3(TBLK, NSPLIT), 256, 0, stream>>>(src, tar, (float*)d_ws);
        nn_sum<<<NPTS / 256, 256, 0, stream>>>(tar, (const float*)d_ws, out);
    } else {
        nn_all<<<NPTS / 256, 256, 0, stream>>>(src, tar, out);
    }
}